// Round 1
// baseline (1995.846 us; speedup 1.0000x reference)
//
#include <hip/hip_runtime.h>
#include <math.h>

// Sizes: B=128, NX=512, NT=512, K=256, P=86, D=658 (fp32 in/out).

// ---------------- NT GEMM: C[m,n] = sum_k A[m,k] * B[n,k] ----------------
__global__ __launch_bounds__(256) void gemm_nt_k(const float* __restrict__ A,
    const float* __restrict__ Bm, float* __restrict__ C,
    int M, int N, int Kd, long sA, long sB, long sC)
{
  const int b = blockIdx.z;
  A += (long)b * sA; Bm += (long)b * sB; C += (long)b * sC;
  __shared__ float As[64 * 17];
  __shared__ float Bs[64 * 17];
  const int tid = threadIdx.x;
  const int tx = tid & 15, ty = tid >> 4;
  const int m0 = blockIdx.y * 64, n0 = blockIdx.x * 64;
  float acc[4][4] = {};
  for (int k0 = 0; k0 < Kd; k0 += 16) {
#pragma unroll
    for (int p = 0; p < 4; ++p) {
      int e = tid + p * 256;
      int r = e >> 4, c = e & 15;
      int kcol = k0 + c;
      int mrow = m0 + r;
      As[r * 17 + c] = (mrow < M && kcol < Kd) ? A[(long)mrow * Kd + kcol] : 0.f;
      int nrow = n0 + r;
      Bs[r * 17 + c] = (nrow < N && kcol < Kd) ? Bm[(long)nrow * Kd + kcol] : 0.f;
    }
    __syncthreads();
#pragma unroll
    for (int kk = 0; kk < 16; ++kk) {
      float av[4], bv[4];
#pragma unroll
      for (int i = 0; i < 4; ++i) av[i] = As[(ty * 4 + i) * 17 + kk];
#pragma unroll
      for (int j = 0; j < 4; ++j) bv[j] = Bs[(tx * 4 + j) * 17 + kk];
#pragma unroll
      for (int i = 0; i < 4; ++i)
#pragma unroll
        for (int j = 0; j < 4; ++j) acc[i][j] = fmaf(av[i], bv[j], acc[i][j]);
    }
    __syncthreads();
  }
#pragma unroll
  for (int i = 0; i < 4; ++i) {
    int m = m0 + ty * 4 + i;
    if (m < M) {
      float4 v = make_float4(acc[i][0], acc[i][1], acc[i][2], acc[i][3]);
      *reinterpret_cast<float4*>(&C[(long)m * N + n0 + tx * 4]) = v;
    }
  }
}

// -------- NN GEMM + tanh: C[m,n] = tanh(sum_k A[m,k] * B[k,n]) --------
__global__ __launch_bounds__(256) void gemm_nn_tanh_k(const float* __restrict__ A,
    const float* __restrict__ Bm, float* __restrict__ C,
    int M, int N, int Kd, long sA, long sB, long sC)
{
  const int b = blockIdx.z;
  A += (long)b * sA; Bm += (long)b * sB; C += (long)b * sC;
  __shared__ float As[64 * 17];
  __shared__ float Bs[16 * 64];
  const int tid = threadIdx.x;
  const int tx = tid & 15, ty = tid >> 4;
  const int m0 = blockIdx.y * 64, n0 = blockIdx.x * 64;
  float acc[4][4] = {};
  for (int k0 = 0; k0 < Kd; k0 += 16) {
#pragma unroll
    for (int p = 0; p < 4; ++p) {
      int e = tid + p * 256;
      {
        int r = e >> 4, c = e & 15;
        int mrow = m0 + r, kcol = k0 + c;
        As[r * 17 + c] = (mrow < M && kcol < Kd) ? A[(long)mrow * Kd + kcol] : 0.f;
      }
      {
        int r = e >> 6, c = e & 63;
        int krow = k0 + r;
        Bs[r * 64 + c] = (krow < Kd) ? Bm[(long)krow * N + n0 + c] : 0.f;
      }
    }
    __syncthreads();
#pragma unroll
    for (int kk = 0; kk < 16; ++kk) {
      float av[4], bv[4];
#pragma unroll
      for (int i = 0; i < 4; ++i) av[i] = As[(ty * 4 + i) * 17 + kk];
#pragma unroll
      for (int j = 0; j < 4; ++j) bv[j] = Bs[kk * 64 + tx * 4 + j];
#pragma unroll
      for (int i = 0; i < 4; ++i)
#pragma unroll
        for (int j = 0; j < 4; ++j) acc[i][j] = fmaf(av[i], bv[j], acc[i][j]);
    }
    __syncthreads();
  }
#pragma unroll
  for (int i = 0; i < 4; ++i) {
    int m = m0 + ty * 4 + i;
    if (m < M) {
      float4 v = make_float4(tanhf(acc[i][0]), tanhf(acc[i][1]),
                             tanhf(acc[i][2]), tanhf(acc[i][3]));
      *reinterpret_cast<float4*>(&C[(long)m * N + n0 + tx * 4]) = v;
    }
  }
}

// H_c path: out_acw[b,n] += sum_m w[m]*tanh( (WpT @ C)[m,n] + WxX[m,n] )
// A = WpT [256,512] (NN, k=nt), B = C [512,512] (k rows), Add = WxX, w = w_hx.
__global__ __launch_bounds__(256) void gemm_nn_attn_k(const float* __restrict__ A,
    const float* __restrict__ Bm, const float* __restrict__ Add,
    const float* __restrict__ wv, float* __restrict__ outw)
{
  const int b = blockIdx.z;
  A += (long)b * (256 * 512); Bm += (long)b * (512 * 512); Add += (long)b * (256 * 512);
  __shared__ float As[64 * 17];
  __shared__ float Bs[16 * 64];
  __shared__ float red[16 * 64];
  const int tid = threadIdx.x;
  const int tx = tid & 15, ty = tid >> 4;
  const int m0 = blockIdx.y * 64, n0 = blockIdx.x * 64;
  float acc[4][4] = {};
  for (int k0 = 0; k0 < 512; k0 += 16) {
#pragma unroll
    for (int p = 0; p < 4; ++p) {
      int e = tid + p * 256;
      { int r = e >> 4, c = e & 15; As[r * 17 + c] = A[(long)(m0 + r) * 512 + k0 + c]; }
      { int r = e >> 6, c = e & 63; Bs[r * 64 + c] = Bm[(long)(k0 + r) * 512 + n0 + c]; }
    }
    __syncthreads();
#pragma unroll
    for (int kk = 0; kk < 16; ++kk) {
      float av[4], bv[4];
#pragma unroll
      for (int i = 0; i < 4; ++i) av[i] = As[(ty * 4 + i) * 17 + kk];
#pragma unroll
      for (int j = 0; j < 4; ++j) bv[j] = Bs[kk * 64 + tx * 4 + j];
#pragma unroll
      for (int i = 0; i < 4; ++i)
#pragma unroll
        for (int j = 0; j < 4; ++j) acc[i][j] = fmaf(av[i], bv[j], acc[i][j]);
    }
    __syncthreads();
  }
  float partial[4] = {0.f, 0.f, 0.f, 0.f};
#pragma unroll
  for (int i = 0; i < 4; ++i) {
    int m = m0 + ty * 4 + i;
    float w = wv[m];
#pragma unroll
    for (int j = 0; j < 4; ++j) {
      int n = n0 + tx * 4 + j;
      partial[j] += w * tanhf(acc[i][j] + Add[(long)m * 512 + n]);
    }
  }
#pragma unroll
  for (int j = 0; j < 4; ++j) red[ty * 64 + tx * 4 + j] = partial[j];
  __syncthreads();
  if (tid < 64) {
    float s = 0.f;
#pragma unroll
    for (int t = 0; t < 16; ++t) s += red[t * 64 + tid];
    atomicAdd(&outw[(long)b * 512 + n0 + tid], s);
  }
}

// H_p path: out_apw[b,n] += sum_m w[m]*tanh( (WxX @ C^T)[m,n] + WpT[m,n] )
// A = WxX [256,512] (k=nx), B = C read NT as [nt][nx], Add = WpT, w = w_hp.
__global__ __launch_bounds__(256) void gemm_nt_attn_k(const float* __restrict__ A,
    const float* __restrict__ Bm, const float* __restrict__ Add,
    const float* __restrict__ wv, float* __restrict__ outw)
{
  const int b = blockIdx.z;
  A += (long)b * (256 * 512); Bm += (long)b * (512 * 512); Add += (long)b * (256 * 512);
  __shared__ float As[64 * 17];
  __shared__ float Bs[64 * 17];
  __shared__ float red[16 * 64];
  const int tid = threadIdx.x;
  const int tx = tid & 15, ty = tid >> 4;
  const int m0 = blockIdx.y * 64, n0 = blockIdx.x * 64;
  float acc[4][4] = {};
  for (int k0 = 0; k0 < 512; k0 += 16) {
#pragma unroll
    for (int p = 0; p < 4; ++p) {
      int e = tid + p * 256;
      int r = e >> 4, c = e & 15;
      As[r * 17 + c] = A[(long)(m0 + r) * 512 + k0 + c];
      Bs[r * 17 + c] = Bm[(long)(n0 + r) * 512 + k0 + c];
    }
    __syncthreads();
#pragma unroll
    for (int kk = 0; kk < 16; ++kk) {
      float av[4], bv[4];
#pragma unroll
      for (int i = 0; i < 4; ++i) av[i] = As[(ty * 4 + i) * 17 + kk];
#pragma unroll
      for (int j = 0; j < 4; ++j) bv[j] = Bs[(tx * 4 + j) * 17 + kk];
#pragma unroll
      for (int i = 0; i < 4; ++i)
#pragma unroll
        for (int j = 0; j < 4; ++j) acc[i][j] = fmaf(av[i], bv[j], acc[i][j]);
    }
    __syncthreads();
  }
  float partial[4] = {0.f, 0.f, 0.f, 0.f};
#pragma unroll
  for (int i = 0; i < 4; ++i) {
    int m = m0 + ty * 4 + i;
    float w = wv[m];
#pragma unroll
    for (int j = 0; j < 4; ++j) {
      int n = n0 + tx * 4 + j;
      partial[j] += w * tanhf(acc[i][j] + Add[(long)m * 512 + n]);
    }
  }
#pragma unroll
  for (int j = 0; j < 4; ++j) red[ty * 64 + tx * 4 + j] = partial[j];
  __syncthreads();
  if (tid < 64) {
    float s = 0.f;
#pragma unroll
    for (int t = 0; t < 16; ++t) s += red[t * 64 + tid];
    atomicAdd(&outw[(long)b * 512 + n0 + tid], s);
  }
}

// Softmax over logits + weighted average of x / target; also emit raw logits.
__global__ __launch_bounds__(256) void finalize_k(const float* __restrict__ x,
    const float* __restrict__ tgt, const float* __restrict__ acw,
    const float* __restrict__ apw, float* __restrict__ out_c,
    float* __restrict__ out_p, float* __restrict__ out_acw,
    float* __restrict__ out_apw)
{
  const int b = blockIdx.x;
  const int tid = threadIdx.x;
  __shared__ float probs[512];
  __shared__ float red[256];

  // ---- part A: a_c = softmax(acw[b]), c = a_c @ x[b]  (D=658) ----
  {
    const float* aw = acw + (long)b * 512;
    float lm = -1e30f;
    for (int i = tid; i < 512; i += 256) {
      float v = aw[i];
      out_acw[(long)b * 512 + i] = v;
      lm = fmaxf(lm, v);
    }
    red[tid] = lm; __syncthreads();
    for (int s = 128; s > 0; s >>= 1) {
      if (tid < s) red[tid] = fmaxf(red[tid], red[tid + s]);
      __syncthreads();
    }
    float bmax = red[0]; __syncthreads();
    float ls = 0.f;
    for (int i = tid; i < 512; i += 256) {
      float e = expf(aw[i] - bmax);
      probs[i] = e;
      ls += e;
    }
    red[tid] = ls; __syncthreads();
    for (int s = 128; s > 0; s >>= 1) {
      if (tid < s) red[tid] += red[tid + s];
      __syncthreads();
    }
    float inv = 1.f / red[0];
    __syncthreads();
    for (int d = tid; d < 658; d += 256) {
      float s = 0.f;
      const float* xb = x + (long)b * 512 * 658 + d;
#pragma unroll 4
      for (int nx = 0; nx < 512; ++nx) s += probs[nx] * xb[(long)nx * 658];
      out_c[(long)b * 658 + d] = s * inv;
    }
    __syncthreads();
  }

  // ---- part B: a_p = softmax(apw[b]), p = a_p @ target[b]  (P=86) ----
  {
    const float* aw = apw + (long)b * 512;
    float lm = -1e30f;
    for (int i = tid; i < 512; i += 256) {
      float v = aw[i];
      out_apw[(long)b * 512 + i] = v;
      lm = fmaxf(lm, v);
    }
    red[tid] = lm; __syncthreads();
    for (int s = 128; s > 0; s >>= 1) {
      if (tid < s) red[tid] = fmaxf(red[tid], red[tid + s]);
      __syncthreads();
    }
    float bmax = red[0]; __syncthreads();
    float ls = 0.f;
    for (int i = tid; i < 512; i += 256) {
      float e = expf(aw[i] - bmax);
      probs[i] = e;
      ls += e;
    }
    red[tid] = ls; __syncthreads();
    for (int s = 128; s > 0; s >>= 1) {
      if (tid < s) red[tid] += red[tid + s];
      __syncthreads();
    }
    float inv = 1.f / red[0];
    __syncthreads();
    for (int d = tid; d < 86; d += 256) {
      float s = 0.f;
      const float* tb = tgt + (long)b * 512 * 86 + d;
#pragma unroll 4
      for (int nt = 0; nt < 512; ++nt) s += probs[nt] * tb[(long)nt * 86];
      out_p[(long)b * 86 + d] = s * inv;
    }
  }
}

extern "C" void kernel_launch(void* const* d_in, const int* in_sizes, int n_in,
                              void* d_out, int out_size, void* d_ws, size_t ws_size,
                              hipStream_t stream) {
  const float* x    = (const float*)d_in[0];  // [128,512,658]
  const float* tgt  = (const float*)d_in[1];  // [128,512,86]
  const float* W_b  = (const float*)d_in[2];  // [86,658]
  const float* W_x  = (const float*)d_in[3];  // [256,658]
  const float* W_p  = (const float*)d_in[4];  // [256,86]
  const float* w_hx = (const float*)d_in[5];  // [256]
  const float* w_hp = (const float*)d_in[6];  // [256]

  float* ws  = (float*)d_ws;
  float* m1  = ws;                             // [128][86][512]
  float* wxx = m1 + (size_t)128 * 86 * 512;    // [128][256][512]
  float* wpt = wxx + (size_t)128 * 256 * 512;  // [128][256][512]
  float* cm  = wpt + (size_t)128 * 256 * 512;  // [128][512][512]
  float* acw = cm + (size_t)128 * 512 * 512;   // [128][512]
  float* apw = acw + (size_t)128 * 512;        // [128][512]

  float* out      = (float*)d_out;
  float* out_c    = out;                        // 128*658
  float* out_p    = out_c + (size_t)128 * 658;  // 128*86
  float* out_acw  = out_p + (size_t)128 * 86;   // 128*512
  float* out_apw  = out_acw + (size_t)128 * 512;

  hipMemsetAsync(acw, 0, sizeof(float) * 2 * 128 * 512, stream);

  dim3 blk(256);
  // M1 = W_b @ x^T : [86,512] per batch
  gemm_nt_k<<<dim3(8, 2, 128), blk, 0, stream>>>(W_b, x, m1, 86, 512, 658,
      0L, (long)512 * 658, (long)86 * 512);
  // WxX = W_x @ x^T : [256,512]
  gemm_nt_k<<<dim3(8, 4, 128), blk, 0, stream>>>(W_x, x, wxx, 256, 512, 658,
      0L, (long)512 * 658, (long)256 * 512);
  // WpT = W_p @ target^T : [256,512]
  gemm_nt_k<<<dim3(8, 4, 128), blk, 0, stream>>>(W_p, tgt, wpt, 256, 512, 86,
      0L, (long)512 * 86, (long)256 * 512);
  // C = tanh(target @ M1) : [512,512]
  gemm_nn_tanh_k<<<dim3(8, 8, 128), blk, 0, stream>>>(tgt, m1, cm, 512, 512, 86,
      (long)512 * 86, (long)86 * 512, (long)512 * 512);
  // acw = sum_k w_hx[k] * tanh(WxX + WpT @ C)
  gemm_nn_attn_k<<<dim3(8, 4, 128), blk, 0, stream>>>(wpt, cm, wxx, w_hx, acw);
  // apw = sum_k w_hp[k] * tanh(WpT + WxX @ C^T)
  gemm_nt_attn_k<<<dim3(8, 4, 128), blk, 0, stream>>>(wxx, cm, wpt, w_hp, apw);
  // softmax + weighted sums + raw logits out
  finalize_k<<<dim3(128), blk, 0, stream>>>(x, tgt, acw, apw,
      out_c, out_p, out_acw, out_apw);
}

// Round 4
// 671.477 us; speedup vs baseline: 2.9723x; 2.9723x over previous
//
#include <hip/hip_runtime.h>
#include <math.h>
#include <stdint.h>

// B=128, NX=512, NT=512, K=256, P=86(pad 96), D=658(pad 672). fp32 in/out.
// Heavy GEMMs: fp16 MFMA (16x16x32_f16), NT layout, 128x128 tile, BK=32,
// 4 waves (2x2) x 64x64 per wave, global_load_lds staging (m97 structure).
// Round 4: bf16 -> fp16 (10-bit mantissa) — bf16 intermediate rounding
// amplified ~5x through the C -> WpT@C -> logit chain exceeded the
// 0.131 threshold (measured 0.231); fp16 cuts every term x8.

typedef _Float16 f16x8 __attribute__((ext_vector_type(8)));
typedef __attribute__((ext_vector_type(4))) float f32x4;

__device__ inline unsigned short f2h(float f) {
  union { _Float16 h; unsigned short u; } v; v.h = (_Float16)f; return v.u;
}
__device__ inline float h2f(unsigned short u) {
  union { unsigned short u; _Float16 h; } v; v.u = u; return (float)v.h;
}

__device__ inline void stage16(const unsigned short* g, unsigned short* l) {
  __builtin_amdgcn_global_load_lds(
      (const __attribute__((address_space(1))) unsigned int*)g,
      (__attribute__((address_space(3))) unsigned int*)l, 16, 0, 0);
}

// NT MFMA GEMM: out[m][n] = sum_k A[m][k]*B[n][k]  (fp16 in, fp32 acc)
// MODE 0: store f16 out (cols < Nstore), row stride ldC
// MODE 1: tanh -> store f16 O[m][n] and transposed O2[n][m]
// MODE 2: v = tanh(acc + Add[m][n]); outw[b][n] += sum_m wv[m]*v
template<int MODE>
__global__ __launch_bounds__(256) void mfma_nt_k(
    const unsigned short* __restrict__ A, const unsigned short* __restrict__ B,
    unsigned short* __restrict__ O, unsigned short* __restrict__ O2,
    const unsigned short* __restrict__ Add, const float* __restrict__ wv,
    float* __restrict__ outw,
    int Kd, int ldA, int ldB, int ldC, int Nstore,
    long sA, long sB, long sO, long sAdd)
{
  const int b = blockIdx.z;
  A += (size_t)b * sA;
  B += (size_t)b * sB;
  const int tid = threadIdx.x;
  const int w = tid >> 6, lane = tid & 63;
  const int wr = w >> 1, wc = w & 1;
  const int m0 = blockIdx.y * 128, n0 = blockIdx.x * 128;

  __shared__ unsigned short As[4096];  // [128 rows][32 k] linear
  __shared__ unsigned short Bs[4096];
  __shared__ float red[128];
  if (MODE == 2 && tid < 128) red[tid] = 0.f;

  // staging: 512 chunks of 16B per 8192B tile; chunk c -> row c>>2, k (c&3)*8.
  // call q (q=0,1): wave w lane l handles chunk q*256 + w*64 + l,
  // LDS byte base (wave-uniform) = q*4096 + w*1024; HW adds lane*16.
  const int c0 = w * 64 + lane;        // chunks 0..255  (rows 0..63)
  const int c1 = c0 + 256;             // chunks 256..511 (rows 64..127)
  const int r0 = c0 >> 2, k0a = (c0 & 3) * 8;
  const int r1 = c1 >> 2, k1a = (c1 & 3) * 8;
  const unsigned short* ga0 = A + (size_t)(m0 + r0) * ldA + k0a;
  const unsigned short* ga1 = A + (size_t)(m0 + r1) * ldA + k1a;
  const unsigned short* gb0 = B + (size_t)(n0 + r0) * ldB + k0a;
  const unsigned short* gb1 = B + (size_t)(n0 + r1) * ldB + k1a;
  unsigned short* la0 = &As[w * 512];          // bytes w*1024
  unsigned short* la1 = &As[2048 + w * 512];   // bytes 4096 + w*1024
  unsigned short* lb0 = &Bs[w * 512];
  unsigned short* lb1 = &Bs[2048 + w * 512];

  f32x4 acc[4][4];
#pragma unroll
  for (int i = 0; i < 4; ++i)
#pragma unroll
    for (int j = 0; j < 4; ++j) acc[i][j] = (f32x4){0.f, 0.f, 0.f, 0.f};

  for (int k0 = 0; k0 < Kd; k0 += 32) {
    stage16(ga0 + k0, la0);
    stage16(ga1 + k0, la1);
    stage16(gb0 + k0, lb0);
    stage16(gb1 + k0, lb1);
    __syncthreads();
    f16x8 af[4], bfr[4];
#pragma unroll
    for (int i = 0; i < 4; ++i)
      af[i] = *(const f16x8*)&As[(wr * 64 + i * 16 + (lane & 15)) * 32 + (lane >> 4) * 8];
#pragma unroll
    for (int j = 0; j < 4; ++j)
      bfr[j] = *(const f16x8*)&Bs[(wc * 64 + j * 16 + (lane & 15)) * 32 + (lane >> 4) * 8];
#pragma unroll
    for (int i = 0; i < 4; ++i)
#pragma unroll
      for (int j = 0; j < 4; ++j)
        acc[i][j] = __builtin_amdgcn_mfma_f32_16x16x32_f16(af[i], bfr[j], acc[i][j], 0, 0, 0);
    __syncthreads();
  }

  if (MODE == 0) {
#pragma unroll
    for (int i = 0; i < 4; ++i) {
      int mb = m0 + wr * 64 + i * 16 + (lane >> 4) * 4;
#pragma unroll
      for (int r = 0; r < 4; ++r) {
#pragma unroll
        for (int j = 0; j < 4; ++j) {
          int n = n0 + wc * 64 + j * 16 + (lane & 15);
          if (n < Nstore)
            O[(size_t)b * sO + (size_t)(mb + r) * ldC + n] = f2h(acc[i][j][r]);
        }
      }
    }
  } else if (MODE == 1) {
    unsigned short* Ob = O + (size_t)b * sO;
    unsigned short* O2b = O2 + (size_t)b * sO;
#pragma unroll
    for (int i = 0; i < 4; ++i) {
      int mb = m0 + wr * 64 + i * 16 + (lane >> 4) * 4;
#pragma unroll
      for (int j = 0; j < 4; ++j) {
        int n = n0 + wc * 64 + j * 16 + (lane & 15);
        unsigned short q[4];
#pragma unroll
        for (int r = 0; r < 4; ++r) {
          q[r] = f2h(tanhf(acc[i][j][r]));
          Ob[(size_t)(mb + r) * 512 + n] = q[r];
        }
        ushort4 pk = make_ushort4(q[0], q[1], q[2], q[3]);
        *reinterpret_cast<ushort4*>(&O2b[(size_t)n * 512 + mb]) = pk;
      }
    }
  } else {  // MODE 2
    Add += (size_t)b * sAdd;
    float part[4] = {0.f, 0.f, 0.f, 0.f};
#pragma unroll
    for (int i = 0; i < 4; ++i) {
      int mb = m0 + wr * 64 + i * 16 + (lane >> 4) * 4;
#pragma unroll
      for (int r = 0; r < 4; ++r) {
        int m = mb + r;
        float wm = wv[m];
#pragma unroll
        for (int j = 0; j < 4; ++j) {
          int n = n0 + wc * 64 + j * 16 + (lane & 15);
          float av = h2f(Add[(size_t)m * 512 + n]);
          part[j] += wm * tanhf(acc[i][j][r] + av);
        }
      }
    }
#pragma unroll
    for (int j = 0; j < 4; ++j)
      atomicAdd(&red[wc * 64 + j * 16 + (lane & 15)], part[j]);
    __syncthreads();
    if (tid < 128) atomicAdd(&outw[(size_t)b * 512 + n0 + tid], red[tid]);
  }
}

// fp32 -> fp16 with zero padding. grid: (rows_dst, ceil(cd/256))
__global__ __launch_bounds__(256) void convpad_k(const float* __restrict__ src,
    unsigned short* __restrict__ dst, int rs, int cs, int cd)
{
  int r = blockIdx.x;
  int c = blockIdx.y * 256 + threadIdx.x;
  if (c >= cd) return;
  float v = (r < rs && c < cs) ? src[(size_t)r * cs + c] : 0.f;
  dst[(size_t)r * cd + c] = f2h(v);
}

// Softmax over logits + weighted average of x / target; emit raw logits.
__global__ __launch_bounds__(256) void finalize_k(const float* __restrict__ x,
    const float* __restrict__ tgt, const float* __restrict__ acw,
    const float* __restrict__ apw, float* __restrict__ out_c,
    float* __restrict__ out_p, float* __restrict__ out_acw,
    float* __restrict__ out_apw)
{
  const int b = blockIdx.x;
  const int tid = threadIdx.x;
  __shared__ float probs[512];
  __shared__ float red[256];

  {  // a_c = softmax(acw[b]), c = a_c @ x[b]  (D=658)
    const float* aw = acw + (long)b * 512;
    float lm = -1e30f;
    for (int i = tid; i < 512; i += 256) {
      float v = aw[i];
      out_acw[(long)b * 512 + i] = v;
      lm = fmaxf(lm, v);
    }
    red[tid] = lm; __syncthreads();
    for (int s = 128; s > 0; s >>= 1) {
      if (tid < s) red[tid] = fmaxf(red[tid], red[tid + s]);
      __syncthreads();
    }
    float bmax = red[0]; __syncthreads();
    float ls = 0.f;
    for (int i = tid; i < 512; i += 256) {
      float e = expf(aw[i] - bmax);
      probs[i] = e;
      ls += e;
    }
    red[tid] = ls; __syncthreads();
    for (int s = 128; s > 0; s >>= 1) {
      if (tid < s) red[tid] += red[tid + s];
      __syncthreads();
    }
    float inv = 1.f / red[0];
    __syncthreads();
    for (int d = tid; d < 658; d += 256) {
      float s = 0.f;
      const float* xb = x + (long)b * 512 * 658 + d;
#pragma unroll 4
      for (int nx = 0; nx < 512; ++nx) s += probs[nx] * xb[(long)nx * 658];
      out_c[(long)b * 658 + d] = s * inv;
    }
    __syncthreads();
  }

  {  // a_p = softmax(apw[b]), p = a_p @ target[b]  (P=86)
    const float* aw = apw + (long)b * 512;
    float lm = -1e30f;
    for (int i = tid; i < 512; i += 256) {
      float v = aw[i];
      out_apw[(long)b * 512 + i] = v;
      lm = fmaxf(lm, v);
    }
    red[tid] = lm; __syncthreads();
    for (int s = 128; s > 0; s >>= 1) {
      if (tid < s) red[tid] = fmaxf(red[tid], red[tid + s]);
      __syncthreads();
    }
    float bmax = red[0]; __syncthreads();
    float ls = 0.f;
    for (int i = tid; i < 512; i += 256) {
      float e = expf(aw[i] - bmax);
      probs[i] = e;
      ls += e;
    }
    red[tid] = ls; __syncthreads();
    for (int s = 128; s > 0; s >>= 1) {
      if (tid < s) red[tid] += red[tid + s];
      __syncthreads();
    }
    float inv = 1.f / red[0];
    __syncthreads();
    for (int d = tid; d < 86; d += 256) {
      float s = 0.f;
      const float* tb = tgt + (long)b * 512 * 86 + d;
#pragma unroll 4
      for (int nt = 0; nt < 512; ++nt) s += probs[nt] * tb[(long)nt * 86];
      out_p[(long)b * 86 + d] = s * inv;
    }
  }
}

extern "C" void kernel_launch(void* const* d_in, const int* in_sizes, int n_in,
                              void* d_out, int out_size, void* d_ws, size_t ws_size,
                              hipStream_t stream) {
  const float* x    = (const float*)d_in[0];  // [128,512,658]
  const float* tgt  = (const float*)d_in[1];  // [128,512,86]
  const float* W_b  = (const float*)d_in[2];  // [86,658]
  const float* W_x  = (const float*)d_in[3];  // [256,658]
  const float* W_p  = (const float*)d_in[4];  // [256,86]
  const float* w_hx = (const float*)d_in[5];  // [256]
  const float* w_hp = (const float*)d_in[6];  // [256]

  // fp16 workspace layout (elements = uint16)
  unsigned short* xb  = (unsigned short*)d_ws;          // [128*512][672]
  unsigned short* tb  = xb  + (size_t)128 * 512 * 672;  // [128*512][96]
  unsigned short* Wxb = tb  + (size_t)128 * 512 * 96;   // [256][672]
  unsigned short* Wbb = Wxb + (size_t)256 * 672;        // [128pad][672]
  unsigned short* Wpb = Wbb + (size_t)128 * 672;        // [256][96]
  unsigned short* m1t = Wpb + (size_t)256 * 96;         // [128][512][96]
  unsigned short* wxx = m1t + (size_t)128 * 512 * 96;   // [128][256][512]
  unsigned short* wpt = wxx + (size_t)128 * 256 * 512;  // [128][256][512]
  unsigned short* cmat= wpt + (size_t)128 * 256 * 512;  // [128][512][512] C
  float* acw = (float*)(cmat + (size_t)128 * 512 * 512);// [128][512]
  float* apw = acw + (size_t)128 * 512;
  unsigned short* ctm = xb;  // C^T aliases xb (dead after GEMM2)

  float* out      = (float*)d_out;
  float* out_c    = out;                        // 128*658
  float* out_p    = out_c + (size_t)128 * 658;  // 128*86
  float* out_acw  = out_p + (size_t)128 * 86;   // 128*512
  float* out_apw  = out_acw + (size_t)128 * 512;

  hipMemsetAsync(acw, 0, sizeof(float) * 2 * 128 * 512, stream);

  dim3 blk(256);
  // fp16 conversions (zero-padded)
  convpad_k<<<dim3(65536, 3), blk, 0, stream>>>(x,   xb,  65536, 658, 672);
  convpad_k<<<dim3(65536, 1), blk, 0, stream>>>(tgt, tb,  65536, 86,  96);
  convpad_k<<<dim3(256, 3),   blk, 0, stream>>>(W_x, Wxb, 256,   658, 672);
  convpad_k<<<dim3(128, 3),   blk, 0, stream>>>(W_b, Wbb, 86,    658, 672);
  convpad_k<<<dim3(256, 1),   blk, 0, stream>>>(W_p, Wpb, 256,   86,  96);

  // G1: M1t[nx][p] = sum_d x[nx][d]*W_b[p][d]   [512 x 96], K=672
  mfma_nt_k<0><<<dim3(1, 4, 128), blk, 0, stream>>>(
      xb, Wbb, m1t, nullptr, nullptr, nullptr, nullptr,
      672, 672, 672, 96, 96, (long)512 * 672, 0L, (long)512 * 96, 0L);
  // G2: WxX[k][nx] = sum_d W_x[k][d]*x[nx][d]   [256 x 512], K=672
  mfma_nt_k<0><<<dim3(4, 2, 128), blk, 0, stream>>>(
      Wxb, xb, wxx, nullptr, nullptr, nullptr, nullptr,
      672, 672, 672, 512, 512, 0L, (long)512 * 672, (long)256 * 512, 0L);
  // G3: WpT[k][nt] = sum_p W_p[k][p]*t[nt][p]   [256 x 512], K=96
  mfma_nt_k<0><<<dim3(4, 2, 128), blk, 0, stream>>>(
      Wpb, tb, wpt, nullptr, nullptr, nullptr, nullptr,
      96, 96, 96, 512, 512, 0L, (long)512 * 96, (long)256 * 512, 0L);
  // G4: C[nt][nx] = tanh(sum_p t[nt][p]*M1t[nx][p]); also C^T  [512x512], K=96
  mfma_nt_k<1><<<dim3(4, 4, 128), blk, 0, stream>>>(
      tb, m1t, cmat, ctm, nullptr, nullptr, nullptr,
      96, 96, 96, 512, 512, (long)512 * 96, (long)512 * 96, (long)512 * 512, 0L);
  // G5: acw[nx] += sum_k w_hx[k]*tanh(WxX[k][nx] + sum_nt WpT[k][nt]*Ct[nx][nt])
  mfma_nt_k<2><<<dim3(4, 2, 128), blk, 0, stream>>>(
      wpt, ctm, nullptr, nullptr, wxx, w_hx, acw,
      512, 512, 512, 512, 512, (long)256 * 512, (long)512 * 512, 0L, (long)256 * 512);
  // G6: apw[nt] += sum_k w_hp[k]*tanh(WpT[k][nt] + sum_nx WxX[k][nx]*C[nt][nx])
  mfma_nt_k<2><<<dim3(4, 2, 128), blk, 0, stream>>>(
      wxx, cmat, nullptr, nullptr, wpt, w_hp, apw,
      512, 512, 512, 512, 512, (long)256 * 512, (long)512 * 512, 0L, (long)256 * 512);
  // softmax + weighted sums + raw logits out
  finalize_k<<<dim3(128), blk, 0, stream>>>(x, tgt, acw, apw,
      out_c, out_p, out_acw, out_apw);
}

// Round 5
// 476.783 us; speedup vs baseline: 4.1861x; 1.4083x over previous
//
#include <hip/hip_runtime.h>
#include <math.h>
#include <stdint.h>

// B=128, NX=512, NT=512, K=256, P=86(pad 96), D=658(pad 672). fp32 in/out.
// Heavy GEMMs: fp16 MFMA (16x16x32_f16), NT layout, 128x128 tile, BK=32,
// 4 waves (2x2) x 64x64 per wave, global_load_lds staging (m97 structure).
// Round 5: finalize_k (250us, 5% occupancy, latency-bound) split into
// softstat_k (softmax stats, 128 blocks) + wsum_k (weighted sum,
// 1536/1024 blocks, LDS probs, 4-acc unroll, atomicAdd epilogue).

typedef _Float16 f16x8 __attribute__((ext_vector_type(8)));
typedef __attribute__((ext_vector_type(4))) float f32x4;

__device__ inline unsigned short f2h(float f) {
  union { _Float16 h; unsigned short u; } v; v.h = (_Float16)f; return v.u;
}
__device__ inline float h2f(unsigned short u) {
  union { unsigned short u; _Float16 h; } v; v.u = u; return (float)v.h;
}

__device__ inline void stage16(const unsigned short* g, unsigned short* l) {
  __builtin_amdgcn_global_load_lds(
      (const __attribute__((address_space(1))) unsigned int*)g,
      (__attribute__((address_space(3))) unsigned int*)l, 16, 0, 0);
}

// NT MFMA GEMM: out[m][n] = sum_k A[m][k]*B[n][k]  (fp16 in, fp32 acc)
// MODE 0: store f16 out (cols < Nstore), row stride ldC
// MODE 1: tanh -> store f16 O[m][n] and transposed O2[n][m]
// MODE 2: v = tanh(acc + Add[m][n]); outw[b][n] += sum_m wv[m]*v
template<int MODE>
__global__ __launch_bounds__(256) void mfma_nt_k(
    const unsigned short* __restrict__ A, const unsigned short* __restrict__ B,
    unsigned short* __restrict__ O, unsigned short* __restrict__ O2,
    const unsigned short* __restrict__ Add, const float* __restrict__ wv,
    float* __restrict__ outw,
    int Kd, int ldA, int ldB, int ldC, int Nstore,
    long sA, long sB, long sO, long sAdd)
{
  const int b = blockIdx.z;
  A += (size_t)b * sA;
  B += (size_t)b * sB;
  const int tid = threadIdx.x;
  const int w = tid >> 6, lane = tid & 63;
  const int wr = w >> 1, wc = w & 1;
  const int m0 = blockIdx.y * 128, n0 = blockIdx.x * 128;

  __shared__ unsigned short As[4096];  // [128 rows][32 k] linear
  __shared__ unsigned short Bs[4096];
  __shared__ float red[128];
  if (MODE == 2 && tid < 128) red[tid] = 0.f;

  // staging: 512 chunks of 16B per 8192B tile; chunk c -> row c>>2, k (c&3)*8.
  const int c0 = w * 64 + lane;        // chunks 0..255  (rows 0..63)
  const int c1 = c0 + 256;             // chunks 256..511 (rows 64..127)
  const int r0 = c0 >> 2, k0a = (c0 & 3) * 8;
  const int r1 = c1 >> 2, k1a = (c1 & 3) * 8;
  const unsigned short* ga0 = A + (size_t)(m0 + r0) * ldA + k0a;
  const unsigned short* ga1 = A + (size_t)(m0 + r1) * ldA + k1a;
  const unsigned short* gb0 = B + (size_t)(n0 + r0) * ldB + k0a;
  const unsigned short* gb1 = B + (size_t)(n0 + r1) * ldB + k1a;
  unsigned short* la0 = &As[w * 512];          // bytes w*1024
  unsigned short* la1 = &As[2048 + w * 512];   // bytes 4096 + w*1024
  unsigned short* lb0 = &Bs[w * 512];
  unsigned short* lb1 = &Bs[2048 + w * 512];

  f32x4 acc[4][4];
#pragma unroll
  for (int i = 0; i < 4; ++i)
#pragma unroll
    for (int j = 0; j < 4; ++j) acc[i][j] = (f32x4){0.f, 0.f, 0.f, 0.f};

  for (int k0 = 0; k0 < Kd; k0 += 32) {
    stage16(ga0 + k0, la0);
    stage16(ga1 + k0, la1);
    stage16(gb0 + k0, lb0);
    stage16(gb1 + k0, lb1);
    __syncthreads();
    f16x8 af[4], bfr[4];
#pragma unroll
    for (int i = 0; i < 4; ++i)
      af[i] = *(const f16x8*)&As[(wr * 64 + i * 16 + (lane & 15)) * 32 + (lane >> 4) * 8];
#pragma unroll
    for (int j = 0; j < 4; ++j)
      bfr[j] = *(const f16x8*)&Bs[(wc * 64 + j * 16 + (lane & 15)) * 32 + (lane >> 4) * 8];
#pragma unroll
    for (int i = 0; i < 4; ++i)
#pragma unroll
      for (int j = 0; j < 4; ++j)
        acc[i][j] = __builtin_amdgcn_mfma_f32_16x16x32_f16(af[i], bfr[j], acc[i][j], 0, 0, 0);
    __syncthreads();
  }

  if (MODE == 0) {
#pragma unroll
    for (int i = 0; i < 4; ++i) {
      int mb = m0 + wr * 64 + i * 16 + (lane >> 4) * 4;
#pragma unroll
      for (int r = 0; r < 4; ++r) {
#pragma unroll
        for (int j = 0; j < 4; ++j) {
          int n = n0 + wc * 64 + j * 16 + (lane & 15);
          if (n < Nstore)
            O[(size_t)b * sO + (size_t)(mb + r) * ldC + n] = f2h(acc[i][j][r]);
        }
      }
    }
  } else if (MODE == 1) {
    unsigned short* Ob = O + (size_t)b * sO;
    unsigned short* O2b = O2 + (size_t)b * sO;
#pragma unroll
    for (int i = 0; i < 4; ++i) {
      int mb = m0 + wr * 64 + i * 16 + (lane >> 4) * 4;
#pragma unroll
      for (int j = 0; j < 4; ++j) {
        int n = n0 + wc * 64 + j * 16 + (lane & 15);
        unsigned short q[4];
#pragma unroll
        for (int r = 0; r < 4; ++r) {
          q[r] = f2h(tanhf(acc[i][j][r]));
          Ob[(size_t)(mb + r) * 512 + n] = q[r];
        }
        ushort4 pk = make_ushort4(q[0], q[1], q[2], q[3]);
        *reinterpret_cast<ushort4*>(&O2b[(size_t)n * 512 + mb]) = pk;
      }
    }
  } else {  // MODE 2
    Add += (size_t)b * sAdd;
    float part[4] = {0.f, 0.f, 0.f, 0.f};
#pragma unroll
    for (int i = 0; i < 4; ++i) {
      int mb = m0 + wr * 64 + i * 16 + (lane >> 4) * 4;
#pragma unroll
      for (int r = 0; r < 4; ++r) {
        int m = mb + r;
        float wm = wv[m];
#pragma unroll
        for (int j = 0; j < 4; ++j) {
          int n = n0 + wc * 64 + j * 16 + (lane & 15);
          float av = h2f(Add[(size_t)m * 512 + n]);
          part[j] += wm * tanhf(acc[i][j][r] + av);
        }
      }
    }
#pragma unroll
    for (int j = 0; j < 4; ++j)
      atomicAdd(&red[wc * 64 + j * 16 + (lane & 15)], part[j]);
    __syncthreads();
    if (tid < 128) atomicAdd(&outw[(size_t)b * 512 + n0 + tid], red[tid]);
  }
}

// fp32 -> fp16 with zero padding. grid: (rows_dst, ceil(cd/256))
__global__ __launch_bounds__(256) void convpad_k(const float* __restrict__ src,
    unsigned short* __restrict__ dst, int rs, int cs, int cd)
{
  int r = blockIdx.x;
  int c = blockIdx.y * 256 + threadIdx.x;
  if (c >= cd) return;
  float v = (r < rs && c < cs) ? src[(size_t)r * cs + c] : 0.f;
  dst[(size_t)r * cd + c] = f2h(v);
}

// Softmax stats: logits -> raw logits out + normalized probs (fp32) in ws.
__global__ __launch_bounds__(256) void softstat_k(const float* __restrict__ acw,
    const float* __restrict__ apw, float* __restrict__ out_acw,
    float* __restrict__ out_apw, float* __restrict__ probs_c,
    float* __restrict__ probs_p)
{
  const int b = blockIdx.x, tid = threadIdx.x;
  __shared__ float red[256];
#pragma unroll
  for (int pass = 0; pass < 2; ++pass) {
    const float* aw = (pass ? apw : acw) + (size_t)b * 512;
    float* ow = (pass ? out_apw : out_acw) + (size_t)b * 512;
    float* pr = (pass ? probs_p : probs_c) + (size_t)b * 512;
    float v0 = aw[tid], v1 = aw[tid + 256];
    ow[tid] = v0; ow[tid + 256] = v1;
    red[tid] = fmaxf(v0, v1); __syncthreads();
    for (int s = 128; s > 0; s >>= 1) {
      if (tid < s) red[tid] = fmaxf(red[tid], red[tid + s]);
      __syncthreads();
    }
    float bm = red[0]; __syncthreads();
    float e0 = expf(v0 - bm), e1 = expf(v1 - bm);
    red[tid] = e0 + e1; __syncthreads();
    for (int s = 128; s > 0; s >>= 1) {
      if (tid < s) red[tid] += red[tid + s];
      __syncthreads();
    }
    float inv = 1.f / red[0]; __syncthreads();
    pr[tid] = e0 * inv; pr[tid + 256] = e1 * inv;
  }
}

// out[b][d] += sum_{i in seg} probs[b][n0+i] * src[b][n0+i][d]
// grid: (ceil(Dd/256), N/seg, B); block 256. seg <= 128, seg % 4 == 0.
__global__ __launch_bounds__(256) void wsum_k(const float* __restrict__ src,
    const float* __restrict__ probs, float* __restrict__ out, int N, int Dd, int seg)
{
  const int b = blockIdx.z;
  const int d = blockIdx.x * 256 + threadIdx.x;
  const int n0 = blockIdx.y * seg;
  __shared__ float pl[128];
  if (threadIdx.x < seg) pl[threadIdx.x] = probs[(size_t)b * N + n0 + threadIdx.x];
  __syncthreads();
  if (d >= Dd) return;
  const float* s = src + ((size_t)b * N + n0) * Dd + d;
  float a0 = 0.f, a1 = 0.f, a2 = 0.f, a3 = 0.f;
  for (int i = 0; i < seg; i += 4) {
    a0 += pl[i]     * s[(size_t)i * Dd];
    a1 += pl[i + 1] * s[(size_t)(i + 1) * Dd];
    a2 += pl[i + 2] * s[(size_t)(i + 2) * Dd];
    a3 += pl[i + 3] * s[(size_t)(i + 3) * Dd];
  }
  atomicAdd(&out[(size_t)b * Dd + d], (a0 + a1) + (a2 + a3));
}

extern "C" void kernel_launch(void* const* d_in, const int* in_sizes, int n_in,
                              void* d_out, int out_size, void* d_ws, size_t ws_size,
                              hipStream_t stream) {
  const float* x    = (const float*)d_in[0];  // [128,512,658]
  const float* tgt  = (const float*)d_in[1];  // [128,512,86]
  const float* W_b  = (const float*)d_in[2];  // [86,658]
  const float* W_x  = (const float*)d_in[3];  // [256,658]
  const float* W_p  = (const float*)d_in[4];  // [256,86]
  const float* w_hx = (const float*)d_in[5];  // [256]
  const float* w_hp = (const float*)d_in[6];  // [256]

  // fp16 workspace layout (elements = uint16)
  unsigned short* xb  = (unsigned short*)d_ws;          // [128*512][672]
  unsigned short* tb  = xb  + (size_t)128 * 512 * 672;  // [128*512][96]
  unsigned short* Wxb = tb  + (size_t)128 * 512 * 96;   // [256][672]
  unsigned short* Wbb = Wxb + (size_t)256 * 672;        // [128pad][672]
  unsigned short* Wpb = Wbb + (size_t)128 * 672;        // [256][96]
  unsigned short* m1t = Wpb + (size_t)256 * 96;         // [128][512][96]
  unsigned short* wxx = m1t + (size_t)128 * 512 * 96;   // [128][256][512]
  unsigned short* wpt = wxx + (size_t)128 * 256 * 512;  // [128][256][512]
  unsigned short* cmat= wpt + (size_t)128 * 256 * 512;  // [128][512][512] C
  float* acw = (float*)(cmat + (size_t)128 * 512 * 512);// [128][512]
  float* apw = acw + (size_t)128 * 512;
  float* probs_c = apw + (size_t)128 * 512;              // [128][512]
  float* probs_p = probs_c + (size_t)128 * 512;          // [128][512]
  unsigned short* ctm = xb;  // C^T aliases xb (dead after GEMM2)

  float* out      = (float*)d_out;
  float* out_c    = out;                        // 128*658
  float* out_p    = out_c + (size_t)128 * 658;  // 128*86
  float* out_acw  = out_p + (size_t)128 * 86;   // 128*512
  float* out_apw  = out_acw + (size_t)128 * 512;

  hipMemsetAsync(acw, 0, sizeof(float) * 2 * 128 * 512, stream);
  // zero out_c + out_p (contiguous) for the wsum atomics
  hipMemsetAsync(out_c, 0, sizeof(float) * 128 * (658 + 86), stream);

  dim3 blk(256);
  // fp16 conversions (zero-padded)
  convpad_k<<<dim3(65536, 3), blk, 0, stream>>>(x,   xb,  65536, 658, 672);
  convpad_k<<<dim3(65536, 1), blk, 0, stream>>>(tgt, tb,  65536, 86,  96);
  convpad_k<<<dim3(256, 3),   blk, 0, stream>>>(W_x, Wxb, 256,   658, 672);
  convpad_k<<<dim3(128, 3),   blk, 0, stream>>>(W_b, Wbb, 86,    658, 672);
  convpad_k<<<dim3(256, 1),   blk, 0, stream>>>(W_p, Wpb, 256,   86,  96);

  // G1: M1t[nx][p] = sum_d x[nx][d]*W_b[p][d]   [512 x 96], K=672
  mfma_nt_k<0><<<dim3(1, 4, 128), blk, 0, stream>>>(
      xb, Wbb, m1t, nullptr, nullptr, nullptr, nullptr,
      672, 672, 672, 96, 96, (long)512 * 672, 0L, (long)512 * 96, 0L);
  // G2: WxX[k][nx] = sum_d W_x[k][d]*x[nx][d]   [256 x 512], K=672
  mfma_nt_k<0><<<dim3(4, 2, 128), blk, 0, stream>>>(
      Wxb, xb, wxx, nullptr, nullptr, nullptr, nullptr,
      672, 672, 672, 512, 512, 0L, (long)512 * 672, (long)256 * 512, 0L);
  // G3: WpT[k][nt] = sum_p W_p[k][p]*t[nt][p]   [256 x 512], K=96
  mfma_nt_k<0><<<dim3(4, 2, 128), blk, 0, stream>>>(
      Wpb, tb, wpt, nullptr, nullptr, nullptr, nullptr,
      96, 96, 96, 512, 512, 0L, (long)512 * 96, (long)256 * 512, 0L);
  // G4: C[nt][nx] = tanh(sum_p t[nt][p]*M1t[nx][p]); also C^T  [512x512], K=96
  mfma_nt_k<1><<<dim3(4, 4, 128), blk, 0, stream>>>(
      tb, m1t, cmat, ctm, nullptr, nullptr, nullptr,
      96, 96, 96, 512, 512, (long)512 * 96, (long)512 * 96, (long)512 * 512, 0L);
  // G5: acw[nx] += sum_k w_hx[k]*tanh(WxX[k][nx] + sum_nt WpT[k][nt]*Ct[nx][nt])
  mfma_nt_k<2><<<dim3(4, 2, 128), blk, 0, stream>>>(
      wpt, ctm, nullptr, nullptr, wxx, w_hx, acw,
      512, 512, 512, 512, 512, (long)256 * 512, (long)512 * 512, 0L, (long)256 * 512);
  // G6: apw[nt] += sum_k w_hp[k]*tanh(WpT[k][nt] + sum_nx WxX[k][nx]*C[nt][nx])
  mfma_nt_k<2><<<dim3(4, 2, 128), blk, 0, stream>>>(
      wxx, cmat, nullptr, nullptr, wpt, w_hp, apw,
      512, 512, 512, 512, 512, (long)256 * 512, (long)512 * 512, 0L, (long)256 * 512);

  // softmax stats + raw logits out
  softstat_k<<<dim3(128), blk, 0, stream>>>(acw, apw, out_acw, out_apw,
      probs_c, probs_p);
  // c = a_c @ x  (D=658, seg=128 -> grid 3x4x128)
  wsum_k<<<dim3(3, 4, 128), blk, 0, stream>>>(x, probs_c, out_c, 512, 658, 128);
  // p = a_p @ target (D=86, seg=64 -> grid 1x8x128)
  wsum_k<<<dim3(1, 8, 128), blk, 0, stream>>>(tgt, probs_p, out_p, 512, 86, 64);
}